// Round 2
// baseline (371.030 us; speedup 1.0000x reference)
//
#include <hip/hip_runtime.h>
#include <math.h>

#define NB 8192
#define BATCH 2
#define KNN 20
#define BN (BATCH*NB)
#define NE (BN*KNN)        // 327680 edges

#define SLICES 16
#define SLICE_LEN 512      // NB/SLICES
#define CHUNK_LEN 128
#define CPS 4              // chunks per slice
#define NCHUNKS 64         // per node (SLICES*CPS)
#define CAP 64             // candidate buffer per node

__device__ __forceinline__ float gelu_f(float x){
    float x3 = x*x*x;
    float a = 0.7978845608028654f*(x + 0.044715f*x3);
    float e2 = __expf(2.0f*a);
    float th = 1.0f - 2.0f/(e2+1.0f);
    return 0.5f*x*(1.0f+th);
}

__device__ __forceinline__ float dist2(float n2x,float n2y,float n2z,float pw,float4 q){
    // MUST be identical code in cmin and collect for threshold consistency
    return fmaf(n2x, q.x, fmaf(n2y, q.y, fmaf(n2z, q.z, pw + q.w)));
}

__device__ __forceinline__ float wave_sum(float v){
    #pragma unroll
    for (int s=1;s<64;s<<=1) v += __shfl_xor(v, s);
    return v;
}
__device__ __forceinline__ float wave_max(float v){
    #pragma unroll
    for (int s=1;s<64;s<<=1) v = fmaxf(v, __shfl_xor(v, s));
    return v;
}

// ---------------- prep: pos4 {x,y,z,r2}, vel4 {vx,vy,vz,massf} ----------------
__global__ __launch_bounds__(256) void prep_kernel(const float* __restrict__ z,
                                                   float4* __restrict__ pos4,
                                                   float4* __restrict__ vel4){
    int g = blockIdx.x*256 + threadIdx.x;
    if (g >= BN) return;
    const float* zp = z + (size_t)g*7;
    float x = zp[0], y = zp[1], zz = zp[2];
    float r2 = x*x + y*y + zz*zz;
    pos4[g] = make_float4(x, y, zz, r2);
    vel4[g] = make_float4(zp[3], zp[4], zp[5], zp[6]);
}

// ---------------- cond MLP + collapsed constants ----------------
// consts floats: C[2][128]@0, S1[128]@256, S2[128]@384, D[2][64]@512, T1[64]@640
__global__ __launch_bounds__(256) void cond_kernel(const float* __restrict__ t,
        const float* __restrict__ conditioning,
        const float* __restrict__ Wc1, const float* __restrict__ bc1,
        const float* __restrict__ Wc2, const float* __restrict__ bc2,
        const float* __restrict__ Wc3, const float* __restrict__ bc3,
        const float* __restrict__ We1, const float* __restrict__ be1,
        const float* __restrict__ Wn1, const float* __restrict__ bn1,
        float* __restrict__ consts){
    int b = blockIdx.x;
    int tid = threadIdx.x;
    __shared__ float ci[36];
    __shared__ float h1[144];
    __shared__ float h2[144];
    __shared__ float cnd[36];
    float tv = t[b];
    if (tid < 16){
        float f = expf(-9.210340371976184f * (float)tid / 15.0f);
        float a = tv*f;
        ci[tid]    = sinf(a);
        ci[16+tid] = cosf(a);
    }
    if (tid < 4) ci[32+tid] = conditioning[b*4+tid];
    __syncthreads();
    if (tid < 144){
        float acc = bc1[tid];
        for (int c=0;c<36;c++) acc += ci[c]*Wc1[c*144+tid];
        h1[tid] = gelu_f(acc);
    }
    __syncthreads();
    if (tid < 144){
        float acc = bc2[tid];
        for (int c=0;c<144;c++) acc += h1[c]*Wc2[c*144+tid];
        h2[tid] = gelu_f(acc);
    }
    __syncthreads();
    if (tid < 36){
        float acc = bc3[tid];
        for (int c=0;c<144;c++) acc += h2[c]*Wc3[c*36+tid];
        cnd[tid] = acc;
    }
    __syncthreads();
    if (tid < 128){
        float accC = be1[tid], s1 = 0.f, s2 = 0.f;
        for (int c=0;c<36;c++){
            float w1 = We1[c*128+tid];
            float w2 = We1[(36+c)*128+tid];
            accC += cnd[c]*(w1+w2);
            s1 += w1; s2 += w2;
        }
        consts[b*128+tid] = accC;
        if (b==0){ consts[256+tid] = s1; consts[384+tid] = s2; }
    }
    if (tid < 64){
        float accD = bn1[tid], t1 = 0.f;
        for (int c=0;c<36;c++){
            float w = Wn1[c*64+tid];
            accD += cnd[c]*w;
            t1 += w;
        }
        consts[512 + b*64 + tid] = accD;
        if (b==0) consts[640+tid] = t1;
    }
}

// ---------------- KNN phase 1: chunk minima (lane-owns-node, uniform cand loads) ----------------
// 64-thread blocks so slice/node-block decode is blockIdx-only => scalar loads for P[j]
__global__ __launch_bounds__(64, 4) void cmin_kernel(const float4* __restrict__ pos4,
                                                     float* __restrict__ cmin){
    int wid = blockIdx.x;              // 0..4095
    int lane = threadIdx.x;
    int s  = wid & 15;
    int nb = (wid >> 4) & 127;
    int b  = wid >> 11;
    int n0 = nb * 64;
    const float4* __restrict__ P = pos4 + b*NB;
    float4 pi = P[n0 + lane];
    float pw = pi.w;
    float n2x = -2.0f*pi.x, n2y = -2.0f*pi.y, n2z = -2.0f*pi.z;
    int jbase = s * SLICE_LEN;
    bool selfslice = (s == (n0 >> 9));
    int gbase = b*NB + n0 + lane;
    for (int tc = 0; tc < CPS; ++tc){
        float cm = 3.0e38f;
        int cb = jbase + tc*CHUNK_LEN;
        if (selfslice){
            #pragma unroll 8
            for (int u = 0; u < CHUNK_LEN; ++u){
                int j = cb + u;
                float4 q = P[j];
                float d2 = dist2(n2x,n2y,n2z,pw,q);
                if (j == n0 + lane) d2 = 3.0e38f;   // exclude self
                cm = fminf(cm, d2);
            }
        } else {
            #pragma unroll 8
            for (int u = 0; u < CHUNK_LEN; ++u){
                float4 q = P[cb + u];
                cm = fminf(cm, dist2(n2x,n2y,n2z,pw,q));
            }
        }
        cmin[(size_t)(s*CPS + tc)*BN + gbase] = cm;
    }
}

// ---------------- KNN phase 2: T = 20th smallest of 64 chunk minima ----------------
__global__ __launch_bounds__(256) void thresh_kernel(const float* __restrict__ cmin,
                                                     float* __restrict__ Tout){
    int g = blockIdx.x*4 + (threadIdx.x>>6);
    int lane = threadIdx.x & 63;
    float a = cmin[(size_t)lane*BN + g];
    float T = 3.0e38f;
    for (int r=0; r<KNN; ++r){
        float m = a;
        #pragma unroll
        for (int s=1;s<64;s<<=1) m = fminf(m, __shfl_xor(m, s));
        if (a == m) a = 3.0e38f;   // pop (multi-pop on ties only loosens T upward-safe)
        T = m;
    }
    if (lane == 0) Tout[g] = T;
}

// ---------------- KNN phase 3: collect all candidates with d2 <= T ----------------
__global__ __launch_bounds__(64, 4) void collect_kernel(const float4* __restrict__ pos4,
        const float* __restrict__ Tin,
        float2* __restrict__ cand, int* __restrict__ cnt){
    int wid = blockIdx.x;
    int lane = threadIdx.x;
    int s  = wid & 15;
    int nb = (wid >> 4) & 127;
    int b  = wid >> 11;
    int n0 = nb * 64;
    const float4* __restrict__ P = pos4 + b*NB;
    float4 pi = P[n0 + lane];
    float pw = pi.w;
    float n2x = -2.0f*pi.x, n2y = -2.0f*pi.y, n2z = -2.0f*pi.z;
    int g = b*NB + n0 + lane;
    float T = Tin[g];
    int jbase = s * SLICE_LEN;
    bool selfslice = (s == (n0 >> 9));
    if (selfslice){
        for (int u = 0; u < SLICE_LEN; ++u){
            int j = jbase + u;
            float4 q = P[j];
            float d2 = dist2(n2x,n2y,n2z,pw,q);
            if (d2 <= T && j != n0 + lane){
                int slot = atomicAdd(&cnt[g], 1);
                if (slot < CAP) cand[(size_t)g*CAP + slot] = make_float2(d2, __int_as_float(j));
            }
        }
    } else {
        for (int u = 0; u < SLICE_LEN; ++u){
            int j = jbase + u;
            float4 q = P[j];
            float d2 = dist2(n2x,n2y,n2z,pw,q);
            if (d2 <= T){
                int slot = atomicAdd(&cnt[g], 1);
                if (slot < CAP) cand[(size_t)g*CAP + slot] = make_float2(d2, __int_as_float(j));
            }
        }
    }
}

// ---------------- KNN phase 4: bitonic-64 by (d2, idx), emit sorted top-20 ----------------
__global__ __launch_bounds__(256) void select_kernel(const float2* __restrict__ cand,
        const int* __restrict__ cnt, int* __restrict__ nbr){
    int g = blockIdx.x*4 + (threadIdx.x>>6);
    int lane = threadIdx.x & 63;
    int m = cnt[g]; if (m > CAP) m = CAP;
    float d; int idx;
    if (lane < m){
        float2 e = cand[(size_t)g*CAP + lane];
        d = e.x; idx = __float_as_int(e.y);
    } else { d = 3.0e38f; idx = 0x7f000000 + lane; }
    #pragma unroll
    for (int k=2; k<=64; k<<=1){
        #pragma unroll
        for (int j=k>>1; j>0; j>>=1){
            float od = __shfl_xor(d, j);
            int   oi = __shfl_xor(idx, j);
            bool up = ((lane & k) == 0);
            bool pless = (od < d) || (od == d && oi < idx);
            bool keepmin = (((lane & j) == 0) == up);
            if (pless == keepmin){ d = od; idx = oi; }
        }
    }
    if (lane < KNN) nbr[(size_t)g*KNN + lane] = idx;
}

// ---------------- edge MLP (collapsed), thread per edge ----------------
// ebuf: logit[NE], smsg[NE], ux[NE], uy[NE], uz[NE]
__global__ __launch_bounds__(256) void edge_kernel(const float4* __restrict__ pos4,
        const float4* __restrict__ vel4,
        const int* __restrict__ nbr,
        const float* __restrict__ consts,
        const float* __restrict__ We1,
        const float* __restrict__ We2,
        const float* __restrict__ be2,
        float* __restrict__ ebuf){
    __shared__ float4 sCA[128], sCB[128], sW2[128];
    int tid = threadIdx.x;
    if (tid < 128){
        sCA[tid] = make_float4(consts[tid], consts[128+tid], consts[256+tid], consts[384+tid]);
        sCB[tid] = make_float4(We1[72*128+tid], We1[73*128+tid], We1[74*128+tid], We1[75*128+tid]);
        sW2[tid] = ((const float4*)We2)[tid];
    }
    __syncthreads();

    int e = blockIdx.x*256 + tid;
    int i = e / KNN;
    int b = i >> 13;
    int s = nbr[e];
    float4 ps = pos4[b*NB + s];
    float4 pt = pos4[i];
    float4 vs = vel4[b*NB + s];
    float4 vt = vel4[i];
    float rx = ps.x - pt.x, ry = ps.y - pt.y, rz = ps.z - pt.z;
    float r2  = rx*rx + ry*ry + rz*rz;
    float vv  = vs.x*vt.x + vs.y*vt.y + vs.z*vt.z;
    float vsr = vs.x*rx + vs.y*ry + vs.z*rz;
    float vtr = vt.x*rx + vt.y*ry + vt.z*rz;
    float mfs = vs.w, mft = vt.w;

    float e0 = be2[0], e1 = be2[1], e2v = be2[2], e3 = be2[3];
    #pragma unroll 4
    for (int h=0; h<128; h++){
        float4 ca = sCA[h];     // {C0,C1,S1,S2} broadcast
        float4 cb = sCB[h];     // {W72,W73,W74,W75}
        float4 w2 = sW2[h];
        float base = b ? ca.y : ca.x;
        float x = base + mfs*ca.z + mft*ca.w + r2*cb.x + vv*cb.y + vsr*cb.z + vtr*cb.w;
        float gx = gelu_f(x);
        e0  += gx*w2.x;
        e1  += gx*w2.y;
        e2v += gx*w2.z;
        e3  += gx*w2.w;
    }
    ebuf[e]        = e0;
    ebuf[NE + e]   = e1;
    ebuf[2*NE + e] = e2v*rx + e3*vs.x;
    ebuf[3*NE + e] = e2v*ry + e3*vs.y;
    ebuf[4*NE + e] = e2v*rz + e3*vs.z;
}

// ---------------- node: softmax + aggregate + node MLP + output, wave per node ----------------
__global__ __launch_bounds__(256) void node_kernel(const float* __restrict__ z,
        const float4* __restrict__ vel4,
        const float* __restrict__ consts,
        const float* __restrict__ Wn1,
        const float* __restrict__ Wn2,
        const float* __restrict__ bn2,
        const float* __restrict__ alpha_p,
        const float* __restrict__ beta_p,
        const float* __restrict__ ebuf,
        float* __restrict__ out){
    int g = blockIdx.x*4 + (threadIdx.x>>6);
    int lane = threadIdx.x & 63;
    int b = g >> 13;

    float lg = -3.0e38f, sm = 0.f, ux = 0.f, uy = 0.f, uz = 0.f;
    if (lane < KNN){
        size_t e = (size_t)g*KNN + lane;
        lg = ebuf[e]; sm = ebuf[NE+e]; ux = ebuf[2*NE+e]; uy = ebuf[3*NE+e]; uz = ebuf[4*NE+e];
    }
    float mx = wave_max(lg);
    float a = (lane < KNN) ? __expf(lg - mx) : 0.0f;
    float denom = wave_sum(a);
    float w = a / denom;
    float sagg = wave_sum(w*sm);
    float vax  = wave_sum(w*ux);
    float vay  = wave_sum(w*uy);
    float vaz  = wave_sum(w*uz);

    float mf = vel4[g].w;
    float x = consts[512 + b*64 + lane] + mf*consts[640+lane] + sagg*Wn1[36*64+lane];
    float y = gelu_f(x)*Wn2[lane];
    float sout = wave_sum(y) + bn2[0];

    if (lane < 7){
        float alpha = alpha_p[0], beta = beta_p[0];
        float zl = z[(size_t)g*7 + lane];
        float r;
        if      (lane==0) r = zl + alpha*vax;
        else if (lane==1) r = zl + alpha*vay;
        else if (lane==2) r = zl + alpha*vaz;
        else if (lane==3) r = beta*vax;
        else if (lane==4) r = beta*vay;
        else if (lane==5) r = beta*vaz;
        else              r = sout;
        out[(size_t)g*7 + lane] = zl + r;
    }
}

extern "C" void kernel_launch(void* const* d_in, const int* in_sizes, int n_in,
                              void* d_out, int out_size, void* d_ws, size_t ws_size,
                              hipStream_t stream) {
    const float* z    = (const float*)d_in[0];
    const float* t    = (const float*)d_in[1];
    const float* cond = (const float*)d_in[2];
    const float* Wc1  = (const float*)d_in[4];
    const float* bc1  = (const float*)d_in[5];
    const float* Wc2  = (const float*)d_in[6];
    const float* bc2  = (const float*)d_in[7];
    const float* Wc3  = (const float*)d_in[8];
    const float* bc3  = (const float*)d_in[9];
    const float* We1  = (const float*)d_in[10];
    const float* be1  = (const float*)d_in[11];
    const float* We2  = (const float*)d_in[12];
    const float* be2  = (const float*)d_in[13];
    const float* Wn1  = (const float*)d_in[14];
    const float* bn1  = (const float*)d_in[15];
    const float* Wn2  = (const float*)d_in[16];
    const float* bn2  = (const float*)d_in[17];
    const float* alp  = (const float*)d_in[18];
    const float* bet  = (const float*)d_in[19];
    float* out = (float*)d_out;

    char* ws = (char*)d_ws;
    float4* pos4   = (float4*)(ws);                      // 262144 B
    float4* vel4   = (float4*)(ws + 262144);             // 262144 B
    float*  consts = (float*)(ws + 524288);              // 4096 B
    float*  Tbuf   = (float*)(ws + 528384);              // 65536 B
    int*    cntb   = (int*)(ws + 593920);                // 65536 B
    int*    nbr    = (int*)(ws + 659456);                // 1310720 B
    float*  cmin   = (float*)(ws + 1970176);             // 64*BN*4 = 4194304 B
    float2* cand   = (float2*)(ws + 6164480);            // BN*64*8 = 8388608 B
    float*  ebuf   = (float*)(ws + 1970176);             // aliases cmin+cand (dead by then)

    prep_kernel<<<dim3(BN/256), dim3(256), 0, stream>>>(z, pos4, vel4);
    cond_kernel<<<dim3(BATCH), dim3(256), 0, stream>>>(t, cond, Wc1, bc1, Wc2, bc2,
                                                       Wc3, bc3, We1, be1, Wn1, bn1, consts);
    hipMemsetAsync(cntb, 0, BN*sizeof(int), stream);
    cmin_kernel<<<dim3(BATCH*128*SLICES), dim3(64), 0, stream>>>(pos4, cmin);
    thresh_kernel<<<dim3(BN/4), dim3(256), 0, stream>>>(cmin, Tbuf);
    collect_kernel<<<dim3(BATCH*128*SLICES), dim3(64), 0, stream>>>(pos4, Tbuf, cand, cntb);
    select_kernel<<<dim3(BN/4), dim3(256), 0, stream>>>(cand, cntb, nbr);
    edge_kernel<<<dim3(NE/256), dim3(256), 0, stream>>>(pos4, vel4, nbr, consts, We1, We2, be2, ebuf);
    node_kernel<<<dim3(BN/4), dim3(256), 0, stream>>>(z, vel4, consts, Wn1, Wn2, bn2,
                                                      alp, bet, ebuf, out);
}

// Round 3
// 292.034 us; speedup vs baseline: 1.2705x; 1.2705x over previous
//
#include <hip/hip_runtime.h>
#include <math.h>

#define NB 8192
#define BATCH 2
#define KNN 20
#define BN (BATCH*NB)
#define NE (BN*KNN)        // 327680 edges
#define CAP 64             // candidate buffer per node
#define NPW 8              // nodes per wave

__device__ __forceinline__ float gelu_f(float x){
    float x3 = x*x*x;
    float a = 0.7978845608028654f*(x + 0.044715f*x3);
    float e2 = __expf(2.0f*a);
    float th = 1.0f - 2.0f/(e2+1.0f);
    return 0.5f*x*(1.0f+th);
}

__device__ __forceinline__ float wave_sum(float v){
    #pragma unroll
    for (int s=1;s<64;s<<=1) v += __shfl_xor(v, s);
    return v;
}
__device__ __forceinline__ float wave_max(float v){
    #pragma unroll
    for (int s=1;s<64;s<<=1) v = fmaxf(v, __shfl_xor(v, s));
    return v;
}

// ---------------- prep: pos4 {x,y,z,r2}, vel4 {vx,vy,vz,massf} ----------------
__global__ __launch_bounds__(256) void prep_kernel(const float* __restrict__ z,
                                                   float4* __restrict__ pos4,
                                                   float4* __restrict__ vel4){
    int g = blockIdx.x*256 + threadIdx.x;
    if (g >= BN) return;
    const float* zp = z + (size_t)g*7;
    float x = zp[0], y = zp[1], zz = zp[2];
    float r2 = x*x + y*y + zz*zz;
    pos4[g] = make_float4(x, y, zz, r2);
    vel4[g] = make_float4(zp[3], zp[4], zp[5], zp[6]);
}

// ---------------- cond MLP + collapsed constants ----------------
// consts floats: C[2][128]@0, S1[128]@256, S2[128]@384, D[2][64]@512, T1[64]@640
__global__ __launch_bounds__(256) void cond_kernel(const float* __restrict__ t,
        const float* __restrict__ conditioning,
        const float* __restrict__ Wc1, const float* __restrict__ bc1,
        const float* __restrict__ Wc2, const float* __restrict__ bc2,
        const float* __restrict__ Wc3, const float* __restrict__ bc3,
        const float* __restrict__ We1, const float* __restrict__ be1,
        const float* __restrict__ Wn1, const float* __restrict__ bn1,
        float* __restrict__ consts){
    int b = blockIdx.x;
    int tid = threadIdx.x;
    __shared__ float ci[36];
    __shared__ float h1[144];
    __shared__ float h2[144];
    __shared__ float cnd[36];
    float tv = t[b];
    if (tid < 16){
        float f = expf(-9.210340371976184f * (float)tid / 15.0f);
        float a = tv*f;
        ci[tid]    = sinf(a);
        ci[16+tid] = cosf(a);
    }
    if (tid < 4) ci[32+tid] = conditioning[b*4+tid];
    __syncthreads();
    if (tid < 144){
        float acc = bc1[tid];
        #pragma unroll 9
        for (int c=0;c<36;c++) acc += ci[c]*Wc1[c*144+tid];
        h1[tid] = gelu_f(acc);
    }
    __syncthreads();
    if (tid < 144){
        float acc = bc2[tid];
        #pragma unroll 8
        for (int c=0;c<144;c++) acc += h1[c]*Wc2[c*144+tid];
        h2[tid] = gelu_f(acc);
    }
    __syncthreads();
    if (tid < 36){
        float acc = bc3[tid];
        #pragma unroll 8
        for (int c=0;c<144;c++) acc += h2[c]*Wc3[c*36+tid];
        cnd[tid] = acc;
    }
    __syncthreads();
    if (tid < 128){
        float accC = be1[tid], s1 = 0.f, s2 = 0.f;
        #pragma unroll 6
        for (int c=0;c<36;c++){
            float w1 = We1[c*128+tid];
            float w2 = We1[(36+c)*128+tid];
            accC += cnd[c]*(w1+w2);
            s1 += w1; s2 += w2;
        }
        consts[b*128+tid] = accC;
        if (b==0){ consts[256+tid] = s1; consts[384+tid] = s2; }
    }
    if (tid < 64){
        float accD = bn1[tid], t1 = 0.f;
        #pragma unroll 6
        for (int c=0;c<36;c++){
            float w = Wn1[c*64+tid];
            accD += cnd[c]*w;
            t1 += w;
        }
        consts[512 + b*64 + tid] = accD;
        if (b==0) consts[640+tid] = t1;
    }
}

// ---------------- fused KNN: lane-owns-candidate, wave-owns-8-nodes ----------------
// Pass A: per-lane min over 128 candidates/lane per node -> bitonic-64 -> T = 20th smallest
// Pass B: rescan, ballot-compact all d2<=T into cand[], count in SGPR (no atomics)
__global__ __launch_bounds__(256) void knn_fused(const float4* __restrict__ pos4,
                                                 float2* __restrict__ cand,
                                                 int* __restrict__ cntb){
    int gw = blockIdx.x*4 + (threadIdx.x>>6);
    int lane = threadIdx.x & 63;
    int n0g = gw*NPW;
    int b = n0g >> 13;
    int n0l = n0g & (NB-1);
    const float4* __restrict__ P = pos4 + b*NB;

    float nx[NPW], ny[NPW], nz[NPW], pw[NPW], acc[NPW];
    #pragma unroll
    for (int k=0;k<NPW;k++){
        float4 p = P[n0l+k];
        nx[k] = -2.0f*p.x; ny[k] = -2.0f*p.y; nz[k] = -2.0f*p.z; pw[k] = p.w;
        acc[k] = 3.0e38f;
    }
    int selfTile = n0l >> 6;        // the 8 selves live in exactly one 64-tile
    int selfBase = n0l & 63;

    // ---- Pass A ----
    #pragma unroll 4
    for (int tk=0; tk<128; ++tk){
        float4 q = P[(tk<<6) + lane];
        if (tk == selfTile){
            #pragma unroll
            for (int k=0;k<NPW;k++){
                float d2 = fmaf(nx[k],q.x, fmaf(ny[k],q.y, fmaf(nz[k],q.z, pw[k]+q.w)));
                if (lane == selfBase + k) d2 = 3.0e38f;
                acc[k] = fminf(acc[k], d2);
            }
        } else {
            #pragma unroll
            for (int k=0;k<NPW;k++){
                float d2 = fmaf(nx[k],q.x, fmaf(ny[k],q.y, fmaf(nz[k],q.z, pw[k]+q.w)));
                acc[k] = fminf(acc[k], d2);
            }
        }
    }

    // ---- T = 20th smallest of the 64 per-lane minima (exact upper bound on d20) ----
    float T[NPW];
    #pragma unroll
    for (int k=0;k<NPW;k++){
        float v = acc[k];
        #pragma unroll
        for (int K=2; K<=64; K<<=1){
            #pragma unroll
            for (int j=K>>1; j>0; j>>=1){
                float o = __shfl_xor(v, j);
                bool up = ((lane & K) == 0);
                bool keepmin = (((lane & j) == 0) == up);
                float mn = fminf(v,o), mx = fmaxf(v,o);
                v = keepmin ? mn : mx;
            }
        }
        T[k] = __shfl(v, 19);
    }

    // ---- Pass B: collect ----
    int cnt[NPW];
    #pragma unroll
    for (int k=0;k<NPW;k++) cnt[k] = 0;
    unsigned long long ltmask = (1ull << lane) - 1ull;

    #pragma unroll 2
    for (int tk=0; tk<128; ++tk){
        int j0 = (tk<<6);
        float4 q = P[j0 + lane];
        bool selft = (tk == selfTile);
        #pragma unroll
        for (int k=0;k<NPW;k++){
            float d2 = fmaf(nx[k],q.x, fmaf(ny[k],q.y, fmaf(nz[k],q.z, pw[k]+q.w)));
            bool hit = (d2 <= T[k]);
            if (selft && (lane == selfBase + k)) hit = false;
            unsigned long long m = __ballot(hit);
            if (m){
                if (hit){
                    int off = cnt[k] + (int)__popcll(m & ltmask);
                    if (off < CAP)
                        cand[(size_t)(n0g+k)*CAP + off] = make_float2(d2, __int_as_float(j0 + lane));
                }
                cnt[k] += (int)__popcll(m);
            }
        }
    }
    if (lane == 0){
        #pragma unroll
        for (int k=0;k<NPW;k++) cntb[n0g+k] = cnt[k];
    }
}

// ---------------- select: bitonic-64 by (d2, idx), emit sorted top-20 ----------------
__global__ __launch_bounds__(256) void select_kernel(const float2* __restrict__ cand,
        const int* __restrict__ cnt, int* __restrict__ nbr){
    int g = blockIdx.x*4 + (threadIdx.x>>6);
    int lane = threadIdx.x & 63;
    int m = cnt[g]; if (m > CAP) m = CAP;
    float d; int idx;
    if (lane < m){
        float2 e = cand[(size_t)g*CAP + lane];
        d = e.x; idx = __float_as_int(e.y);
    } else { d = 3.0e38f; idx = 0x7f000000 + lane; }
    #pragma unroll
    for (int k=2; k<=64; k<<=1){
        #pragma unroll
        for (int j=k>>1; j>0; j>>=1){
            float od = __shfl_xor(d, j);
            int   oi = __shfl_xor(idx, j);
            bool up = ((lane & k) == 0);
            bool pless = (od < d) || (od == d && oi < idx);
            bool keepmin = (((lane & j) == 0) == up);
            if (pless == keepmin){ d = od; idx = oi; }
        }
    }
    if (lane < KNN) nbr[(size_t)g*KNN + lane] = idx;
}

// ---------------- edge MLP (collapsed), thread per edge ----------------
// ebuf: logit[NE], smsg[NE], ux[NE], uy[NE], uz[NE]
__global__ __launch_bounds__(256) void edge_kernel(const float4* __restrict__ pos4,
        const float4* __restrict__ vel4,
        const int* __restrict__ nbr,
        const float* __restrict__ consts,
        const float* __restrict__ We1,
        const float* __restrict__ We2,
        const float* __restrict__ be2,
        float* __restrict__ ebuf){
    __shared__ float4 sCA[128], sCB[128], sW2[128];
    int tid = threadIdx.x;
    if (tid < 128){
        sCA[tid] = make_float4(consts[tid], consts[128+tid], consts[256+tid], consts[384+tid]);
        sCB[tid] = make_float4(We1[72*128+tid], We1[73*128+tid], We1[74*128+tid], We1[75*128+tid]);
        sW2[tid] = ((const float4*)We2)[tid];
    }
    __syncthreads();

    int e = blockIdx.x*256 + tid;
    int i = e / KNN;
    int b = i >> 13;
    int s = nbr[e];
    float4 ps = pos4[b*NB + s];
    float4 pt = pos4[i];
    float4 vs = vel4[b*NB + s];
    float4 vt = vel4[i];
    float rx = ps.x - pt.x, ry = ps.y - pt.y, rz = ps.z - pt.z;
    float r2  = rx*rx + ry*ry + rz*rz;
    float vv  = vs.x*vt.x + vs.y*vt.y + vs.z*vt.z;
    float vsr = vs.x*rx + vs.y*ry + vs.z*rz;
    float vtr = vt.x*rx + vt.y*ry + vt.z*rz;
    float mfs = vs.w, mft = vt.w;

    float e0 = be2[0], e1 = be2[1], e2v = be2[2], e3 = be2[3];
    #pragma unroll 4
    for (int h=0; h<128; h++){
        float4 ca = sCA[h];
        float4 cb = sCB[h];
        float4 w2 = sW2[h];
        float base = b ? ca.y : ca.x;
        float x = base + mfs*ca.z + mft*ca.w + r2*cb.x + vv*cb.y + vsr*cb.z + vtr*cb.w;
        float gx = gelu_f(x);
        e0  += gx*w2.x;
        e1  += gx*w2.y;
        e2v += gx*w2.z;
        e3  += gx*w2.w;
    }
    ebuf[e]        = e0;
    ebuf[NE + e]   = e1;
    ebuf[2*NE + e] = e2v*rx + e3*vs.x;
    ebuf[3*NE + e] = e2v*ry + e3*vs.y;
    ebuf[4*NE + e] = e2v*rz + e3*vs.z;
}

// ---------------- node: softmax + aggregate + node MLP + output, wave per node ----------------
__global__ __launch_bounds__(256) void node_kernel(const float* __restrict__ z,
        const float4* __restrict__ vel4,
        const float* __restrict__ consts,
        const float* __restrict__ Wn1,
        const float* __restrict__ Wn2,
        const float* __restrict__ bn2,
        const float* __restrict__ alpha_p,
        const float* __restrict__ beta_p,
        const float* __restrict__ ebuf,
        float* __restrict__ out){
    int g = blockIdx.x*4 + (threadIdx.x>>6);
    int lane = threadIdx.x & 63;
    int b = g >> 13;

    float lg = -3.0e38f, sm = 0.f, ux = 0.f, uy = 0.f, uz = 0.f;
    if (lane < KNN){
        size_t e = (size_t)g*KNN + lane;
        lg = ebuf[e]; sm = ebuf[NE+e]; ux = ebuf[2*NE+e]; uy = ebuf[3*NE+e]; uz = ebuf[4*NE+e];
    }
    float mx = wave_max(lg);
    float a = (lane < KNN) ? __expf(lg - mx) : 0.0f;
    float denom = wave_sum(a);
    float w = a / denom;
    float sagg = wave_sum(w*sm);
    float vax  = wave_sum(w*ux);
    float vay  = wave_sum(w*uy);
    float vaz  = wave_sum(w*uz);

    float mf = vel4[g].w;
    float x = consts[512 + b*64 + lane] + mf*consts[640+lane] + sagg*Wn1[36*64+lane];
    float y = gelu_f(x)*Wn2[lane];
    float sout = wave_sum(y) + bn2[0];

    if (lane < 7){
        float alpha = alpha_p[0], beta = beta_p[0];
        float zl = z[(size_t)g*7 + lane];
        float r;
        if      (lane==0) r = zl + alpha*vax;
        else if (lane==1) r = zl + alpha*vay;
        else if (lane==2) r = zl + alpha*vaz;
        else if (lane==3) r = beta*vax;
        else if (lane==4) r = beta*vay;
        else if (lane==5) r = beta*vaz;
        else              r = sout;
        out[(size_t)g*7 + lane] = zl + r;
    }
}

extern "C" void kernel_launch(void* const* d_in, const int* in_sizes, int n_in,
                              void* d_out, int out_size, void* d_ws, size_t ws_size,
                              hipStream_t stream) {
    const float* z    = (const float*)d_in[0];
    const float* t    = (const float*)d_in[1];
    const float* cond = (const float*)d_in[2];
    const float* Wc1  = (const float*)d_in[4];
    const float* bc1  = (const float*)d_in[5];
    const float* Wc2  = (const float*)d_in[6];
    const float* bc2  = (const float*)d_in[7];
    const float* Wc3  = (const float*)d_in[8];
    const float* bc3  = (const float*)d_in[9];
    const float* We1  = (const float*)d_in[10];
    const float* be1  = (const float*)d_in[11];
    const float* We2  = (const float*)d_in[12];
    const float* be2  = (const float*)d_in[13];
    const float* Wn1  = (const float*)d_in[14];
    const float* bn1  = (const float*)d_in[15];
    const float* Wn2  = (const float*)d_in[16];
    const float* bn2  = (const float*)d_in[17];
    const float* alp  = (const float*)d_in[18];
    const float* bet  = (const float*)d_in[19];
    float* out = (float*)d_out;

    char* ws = (char*)d_ws;
    float4* pos4   = (float4*)(ws);                      // 262144 B
    float4* vel4   = (float4*)(ws + 262144);             // 262144 B
    float*  consts = (float*)(ws + 524288);              // 4096 B
    int*    cntb   = (int*)(ws + 528384);                // 65536 B
    int*    nbr    = (int*)(ws + 593920);                // 1310720 B
    float2* cand   = (float2*)(ws + 1904640);            // BN*64*8 = 8388608 B
    float*  ebuf   = (float*)(ws + 1904640);             // aliases cand (dead after select)

    prep_kernel<<<dim3(BN/256), dim3(256), 0, stream>>>(z, pos4, vel4);
    cond_kernel<<<dim3(BATCH), dim3(256), 0, stream>>>(t, cond, Wc1, bc1, Wc2, bc2,
                                                       Wc3, bc3, We1, be1, Wn1, bn1, consts);
    knn_fused<<<dim3(BN/(NPW*4)), dim3(256), 0, stream>>>(pos4, cand, cntb);
    select_kernel<<<dim3(BN/4), dim3(256), 0, stream>>>(cand, cntb, nbr);
    edge_kernel<<<dim3(NE/256), dim3(256), 0, stream>>>(pos4, vel4, nbr, consts, We1, We2, be2, ebuf);
    node_kernel<<<dim3(BN/4), dim3(256), 0, stream>>>(z, vel4, consts, Wn1, Wn2, bn2,
                                                      alp, bet, ebuf, out);
}

// Round 4
// 217.689 us; speedup vs baseline: 1.7044x; 1.3415x over previous
//
#include <hip/hip_runtime.h>
#include <math.h>

#define NB 8192
#define BATCH 2
#define KNN 20
#define BN (BATCH*NB)
#define NE (BN*KNN)        // 327680 edges
#define GT 16              // tiles per staged group (16 KB)
#define NG 8               // groups per pass (GT*NG*64 = 8192)

__device__ __forceinline__ float gelu_f(float x){
    float x3 = x*x*x;
    float a = 0.7978845608028654f*(x + 0.044715f*x3);
    float e2 = __expf(2.0f*a);
    float th = 1.0f - 2.0f/(e2+1.0f);
    return 0.5f*x*(1.0f+th);
}

__device__ __forceinline__ float wave_sum(float v){
    #pragma unroll
    for (int s=1;s<64;s<<=1) v += __shfl_xor(v, s);
    return v;
}
__device__ __forceinline__ float wave_max(float v){
    #pragma unroll
    for (int s=1;s<64;s<<=1) v = fmaxf(v, __shfl_xor(v, s));
    return v;
}

// ---------------- prep: pos4 {x,y,z,r2}, vel4 {vx,vy,vz,massf} ----------------
__global__ __launch_bounds__(256) void prep_kernel(const float* __restrict__ z,
                                                   float4* __restrict__ pos4,
                                                   float4* __restrict__ vel4){
    int g = blockIdx.x*256 + threadIdx.x;
    if (g >= BN) return;
    const float* zp = z + (size_t)g*7;
    float x = zp[0], y = zp[1], zz = zp[2];
    float r2 = x*x + y*y + zz*zz;
    pos4[g] = make_float4(x, y, zz, r2);
    vel4[g] = make_float4(zp[3], zp[4], zp[5], zp[6]);
}

// ---------------- cond MLP + collapsed constants + packed edge weights ----------------
// consts floats: C[2][128]@0, S1[128]@256, S2[128]@384, D[2][64]@512, T1[64]@640
// pack: per h (128): {C0,C1,S1,S2,W72,W73,W74,W75,V0,V1,V2,V3} = 12 floats
__global__ __launch_bounds__(256) void cond_kernel(const float* __restrict__ t,
        const float* __restrict__ conditioning,
        const float* __restrict__ Wc1, const float* __restrict__ bc1,
        const float* __restrict__ Wc2, const float* __restrict__ bc2,
        const float* __restrict__ Wc3, const float* __restrict__ bc3,
        const float* __restrict__ We1, const float* __restrict__ be1,
        const float* __restrict__ We2,
        const float* __restrict__ Wn1, const float* __restrict__ bn1,
        float* __restrict__ consts, float* __restrict__ pack){
    int b = blockIdx.x;
    int tid = threadIdx.x;
    __shared__ float ci[36];
    __shared__ float h1[144];
    __shared__ float h2[144];
    __shared__ float cnd[36];
    float tv = t[b];
    if (tid < 16){
        float f = expf(-9.210340371976184f * (float)tid / 15.0f);
        float a = tv*f;
        ci[tid]    = sinf(a);
        ci[16+tid] = cosf(a);
    }
    if (tid < 4) ci[32+tid] = conditioning[b*4+tid];
    __syncthreads();
    if (tid < 144){
        float acc = bc1[tid];
        #pragma unroll
        for (int c=0;c<36;c++) acc += ci[c]*Wc1[c*144+tid];
        h1[tid] = gelu_f(acc);
    }
    __syncthreads();
    if (tid < 144){
        float acc = bc2[tid];
        #pragma unroll 36
        for (int c=0;c<144;c++) acc += h1[c]*Wc2[c*144+tid];
        h2[tid] = gelu_f(acc);
    }
    __syncthreads();
    if (tid < 36){
        float acc = bc3[tid];
        #pragma unroll 36
        for (int c=0;c<144;c++) acc += h2[c]*Wc3[c*36+tid];
        cnd[tid] = acc;
    }
    __syncthreads();
    if (tid < 128){
        float accC = be1[tid], s1 = 0.f, s2 = 0.f;
        #pragma unroll
        for (int c=0;c<36;c++){
            float w1 = We1[c*128+tid];
            float w2 = We1[(36+c)*128+tid];
            accC += cnd[c]*(w1+w2);
            s1 += w1; s2 += w2;
        }
        consts[b*128+tid] = accC;
        pack[tid*12 + b] = accC;               // C0 or C1
        if (b==0){
            consts[256+tid] = s1; consts[384+tid] = s2;
            pack[tid*12+2] = s1;
            pack[tid*12+3] = s2;
            pack[tid*12+4] = We1[72*128+tid];
            pack[tid*12+5] = We1[73*128+tid];
            pack[tid*12+6] = We1[74*128+tid];
            pack[tid*12+7] = We1[75*128+tid];
            pack[tid*12+8]  = We2[tid*4+0];
            pack[tid*12+9]  = We2[tid*4+1];
            pack[tid*12+10] = We2[tid*4+2];
            pack[tid*12+11] = We2[tid*4+3];
        }
    }
    if (tid < 64){
        float accD = bn1[tid], t1 = 0.f;
        #pragma unroll
        for (int c=0;c<36;c++){
            float w = Wn1[c*64+tid];
            accD += cnd[c]*w;
            t1 += w;
        }
        consts[512 + b*64 + tid] = accD;
        if (b==0) consts[640+tid] = t1;
    }
}

// ---------------- fused KNN + select: LDS-staged tiles, 8 waves x 4 nodes/block ----------------
// Pass A: per-lane min (lane l covers {t*64+l}) -> bitonic-64 -> T = 20th smallest (exact bound)
// Pass B: rescan from LDS, ballot-compact d2<=T into LDS cand, bitonic by (d2,idx), emit top-20
__global__ __launch_bounds__(512, 4) void knn_kernel(const float4* __restrict__ pos4,
                                                     int* __restrict__ nbr){
    __shared__ float4 sPos[GT*64];      // 16 KB
    __shared__ float2 sCand[32*64];     // 16 KB
    int tid = threadIdx.x;
    int w = tid >> 6, lane = tid & 63;
    int n0g = blockIdx.x * 32;
    int b = n0g >> 13;
    int n0 = n0g & (NB-1);
    const float4* __restrict__ P = pos4 + b*NB;

    int nw = n0 + w*4;
    float nx[4], ny[4], nz[4], pw[4], acc[4];
    #pragma unroll
    for (int k=0;k<4;k++){
        float4 p = P[nw+k];
        nx[k] = -2.0f*p.x; ny[k] = -2.0f*p.y; nz[k] = -2.0f*p.z; pw[k] = p.w;
        acc[k] = 3.0e38f;
    }
    int selfTile = n0 >> 6;            // all 32 block nodes share one tile
    int sl0 = (n0 & 63) + w*4;         // self lane for node k is sl0+k

    // ---- Pass A ----
    float4 pre0 = P[(w*2    )*64 + lane];
    float4 pre1 = P[(w*2 + 1)*64 + lane];
    for (int g=0; g<NG; ++g){
        __syncthreads();
        sPos[(w*2    )*64 + lane] = pre0;
        sPos[(w*2 + 1)*64 + lane] = pre1;
        if (g+1 < NG){
            pre0 = P[((g+1)*GT + w*2    )*64 + lane];
            pre1 = P[((g+1)*GT + w*2 + 1)*64 + lane];
        }
        __syncthreads();
        int tbase = g*GT;
        #pragma unroll
        for (int t=0;t<GT;t++){
            float4 q = sPos[t*64 + lane];
            if (tbase + t != selfTile){
                #pragma unroll
                for (int k=0;k<4;k++){
                    float d2 = fmaf(nx[k],q.x, fmaf(ny[k],q.y, fmaf(nz[k],q.z, pw[k]+q.w)));
                    acc[k] = fminf(acc[k], d2);
                }
            } else {
                #pragma unroll
                for (int k=0;k<4;k++){
                    float d2 = fmaf(nx[k],q.x, fmaf(ny[k],q.y, fmaf(nz[k],q.z, pw[k]+q.w)));
                    if (lane == sl0 + k) d2 = 3.0e38f;
                    acc[k] = fminf(acc[k], d2);
                }
            }
        }
    }

    // ---- T[k] = 20th smallest of 64 per-lane minima ----
    float T[4];
    #pragma unroll
    for (int k=0;k<4;k++){
        float v = acc[k];
        #pragma unroll
        for (int K=2; K<=64; K<<=1){
            #pragma unroll
            for (int j=K>>1; j>0; j>>=1){
                float o = __shfl_xor(v, j);
                bool keepmin = (((lane & j) == 0) == ((lane & K) == 0));
                float mn = fminf(v,o), mx = fmaxf(v,o);
                v = keepmin ? mn : mx;
            }
        }
        T[k] = __shfl(v, 19);
    }

    // ---- Pass B: collect into LDS ----
    int cnt[4];
    #pragma unroll
    for (int k=0;k<4;k++) cnt[k] = 0;
    unsigned long long lt = (1ull << lane) - 1ull;

    pre0 = P[(w*2    )*64 + lane];
    pre1 = P[(w*2 + 1)*64 + lane];
    for (int g=0; g<NG; ++g){
        __syncthreads();
        sPos[(w*2    )*64 + lane] = pre0;
        sPos[(w*2 + 1)*64 + lane] = pre1;
        if (g+1 < NG){
            pre0 = P[((g+1)*GT + w*2    )*64 + lane];
            pre1 = P[((g+1)*GT + w*2 + 1)*64 + lane];
        }
        __syncthreads();
        int tbase = g*GT;
        #pragma unroll 4
        for (int t=0;t<GT;t++){
            int tile = tbase + t;
            float4 q = sPos[t*64 + lane];
            int j = (tile<<6) + lane;
            bool selft = (tile == selfTile);
            #pragma unroll
            for (int k=0;k<4;k++){
                float d2 = fmaf(nx[k],q.x, fmaf(ny[k],q.y, fmaf(nz[k],q.z, pw[k]+q.w)));
                bool hit = (d2 <= T[k]);
                if (selft && (lane == sl0 + k)) hit = false;
                unsigned long long m = __ballot(hit);
                if (m){
                    if (hit){
                        int off = cnt[k] + (int)__popcll(m & lt);
                        if (off < 64)
                            sCand[(w*4+k)*64 + off] = make_float2(d2, __int_as_float(j));
                    }
                    cnt[k] += (int)__popcll(m);
                }
            }
        }
    }

    // ---- sort each node's candidates (same-wave data; no barrier needed) ----
    #pragma unroll
    for (int k=0;k<4;k++){
        int m = cnt[k]; if (m > 64) m = 64;
        float d; int idx;
        if (lane < m){
            float2 e = sCand[(w*4+k)*64 + lane];
            d = e.x; idx = __float_as_int(e.y);
        } else { d = 3.0e38f; idx = 0x7f000000 + lane; }
        #pragma unroll
        for (int K=2; K<=64; K<<=1){
            #pragma unroll
            for (int j=K>>1; j>0; j>>=1){
                float od = __shfl_xor(d, j);
                int   oi = __shfl_xor(idx, j);
                bool pless = (od < d) || (od == d && oi < idx);
                bool keepmin = (((lane & j) == 0) == ((lane & K) == 0));
                if (pless == keepmin){ d = od; idx = oi; }
            }
        }
        if (lane < KNN) nbr[(size_t)(n0g + w*4 + k)*KNN + lane] = idx;
    }
}

// ---------------- edge MLP (collapsed), thread per edge, s_load weights ----------------
// ebuf: logit[NE], smsg[NE], ux[NE], uy[NE], uz[NE]
__global__ __launch_bounds__(256) void edge_kernel(const float4* __restrict__ pos4,
        const float4* __restrict__ vel4,
        const int* __restrict__ nbr,
        const float* __restrict__ pack,
        const float* __restrict__ be2,
        float* __restrict__ ebuf){
    int tid = threadIdx.x;
    bool bb = (blockIdx.x >= (NE/2/256));   // batch is block-uniform (163840 = 640*256)

    int e = blockIdx.x*256 + tid;
    int i = e / KNN;
    int b = i >> 13;
    int s = nbr[e];
    float4 ps = pos4[b*NB + s];
    float4 pt = pos4[i];
    float4 vs = vel4[b*NB + s];
    float4 vt = vel4[i];
    float rx = ps.x - pt.x, ry = ps.y - pt.y, rz = ps.z - pt.z;
    float r2  = rx*rx + ry*ry + rz*rz;
    float vv  = vs.x*vt.x + vs.y*vt.y + vs.z*vt.z;
    float vsr = vs.x*rx + vs.y*ry + vs.z*rz;
    float vtr = vt.x*rx + vt.y*ry + vt.z*rz;
    float mfs = vs.w, mft = vt.w;

    float e0 = be2[0], e1 = be2[1], e2v = be2[2], e3 = be2[3];
    #pragma unroll 8
    for (int h=0; h<128; h++){
        const float4* pb = (const float4*)(pack + h*12);  // wave-uniform -> s_load
        float4 A = pb[0];   // {C0,C1,S1,S2}
        float4 Bv = pb[1];  // {W72,W73,W74,W75}
        float4 C = pb[2];   // We2 row
        float base = bb ? A.y : A.x;
        float x = base + mfs*A.z + mft*A.w + r2*Bv.x + vv*Bv.y + vsr*Bv.z + vtr*Bv.w;
        float gx = gelu_f(x);
        e0  += gx*C.x;
        e1  += gx*C.y;
        e2v += gx*C.z;
        e3  += gx*C.w;
    }
    ebuf[e]        = e0;
    ebuf[NE + e]   = e1;
    ebuf[2*NE + e] = e2v*rx + e3*vs.x;
    ebuf[3*NE + e] = e2v*ry + e3*vs.y;
    ebuf[4*NE + e] = e2v*rz + e3*vs.z;
}

// ---------------- node: softmax + aggregate + node MLP + output, wave per node ----------------
__global__ __launch_bounds__(256) void node_kernel(const float* __restrict__ z,
        const float4* __restrict__ vel4,
        const float* __restrict__ consts,
        const float* __restrict__ Wn1,
        const float* __restrict__ Wn2,
        const float* __restrict__ bn2,
        const float* __restrict__ alpha_p,
        const float* __restrict__ beta_p,
        const float* __restrict__ ebuf,
        float* __restrict__ out){
    int g = blockIdx.x*4 + (threadIdx.x>>6);
    int lane = threadIdx.x & 63;
    int b = g >> 13;

    float lg = -3.0e38f, sm = 0.f, ux = 0.f, uy = 0.f, uz = 0.f;
    if (lane < KNN){
        size_t e = (size_t)g*KNN + lane;
        lg = ebuf[e]; sm = ebuf[NE+e]; ux = ebuf[2*NE+e]; uy = ebuf[3*NE+e]; uz = ebuf[4*NE+e];
    }
    float mx = wave_max(lg);
    float a = (lane < KNN) ? __expf(lg - mx) : 0.0f;
    float denom = wave_sum(a);
    float wv = a / denom;
    float sagg = wave_sum(wv*sm);
    float vax  = wave_sum(wv*ux);
    float vay  = wave_sum(wv*uy);
    float vaz  = wave_sum(wv*uz);

    float mf = vel4[g].w;
    float x = consts[512 + b*64 + lane] + mf*consts[640+lane] + sagg*Wn1[36*64+lane];
    float y = gelu_f(x)*Wn2[lane];
    float sout = wave_sum(y) + bn2[0];

    if (lane < 7){
        float alpha = alpha_p[0], beta = beta_p[0];
        float zl = z[(size_t)g*7 + lane];
        float r;
        if      (lane==0) r = zl + alpha*vax;
        else if (lane==1) r = zl + alpha*vay;
        else if (lane==2) r = zl + alpha*vaz;
        else if (lane==3) r = beta*vax;
        else if (lane==4) r = beta*vay;
        else if (lane==5) r = beta*vaz;
        else              r = sout;
        out[(size_t)g*7 + lane] = zl + r;
    }
}

extern "C" void kernel_launch(void* const* d_in, const int* in_sizes, int n_in,
                              void* d_out, int out_size, void* d_ws, size_t ws_size,
                              hipStream_t stream) {
    const float* z    = (const float*)d_in[0];
    const float* t    = (const float*)d_in[1];
    const float* cond = (const float*)d_in[2];
    const float* Wc1  = (const float*)d_in[4];
    const float* bc1  = (const float*)d_in[5];
    const float* Wc2  = (const float*)d_in[6];
    const float* bc2  = (const float*)d_in[7];
    const float* Wc3  = (const float*)d_in[8];
    const float* bc3  = (const float*)d_in[9];
    const float* We1  = (const float*)d_in[10];
    const float* be1  = (const float*)d_in[11];
    const float* We2  = (const float*)d_in[12];
    const float* be2  = (const float*)d_in[13];
    const float* Wn1  = (const float*)d_in[14];
    const float* bn1  = (const float*)d_in[15];
    const float* Wn2  = (const float*)d_in[16];
    const float* bn2  = (const float*)d_in[17];
    const float* alp  = (const float*)d_in[18];
    const float* bet  = (const float*)d_in[19];
    float* out = (float*)d_out;

    char* ws = (char*)d_ws;
    float4* pos4   = (float4*)(ws);                      // 262144 B
    float4* vel4   = (float4*)(ws + 262144);             // 262144 B
    float*  consts = (float*)(ws + 524288);              // 4096 B
    float*  pack   = (float*)(ws + 528384);              // 6144 B
    int*    nbr    = (int*)(ws + 534528);                // 1310720 B
    float*  ebuf   = (float*)(ws + 1845248);             // 6553600 B

    prep_kernel<<<dim3(BN/256), dim3(256), 0, stream>>>(z, pos4, vel4);
    cond_kernel<<<dim3(BATCH), dim3(256), 0, stream>>>(t, cond, Wc1, bc1, Wc2, bc2,
                                                       Wc3, bc3, We1, be1, We2, Wn1, bn1,
                                                       consts, pack);
    knn_kernel<<<dim3(BN/32), dim3(512), 0, stream>>>(pos4, nbr);
    edge_kernel<<<dim3(NE/256), dim3(256), 0, stream>>>(pos4, vel4, nbr, pack, be2, ebuf);
    node_kernel<<<dim3(BN/4), dim3(256), 0, stream>>>(z, vel4, consts, Wn1, Wn2, bn2,
                                                      alp, bet, ebuf, out);
}